// Round 3
// baseline (2389.505 us; speedup 1.0000x reference)
//
#include <hip/hip_runtime.h>

// VQ-VAE vector quantize + losses, MI355X fp32.
// T=8192 rows (b*h*w), N_E=16384 codes, D=32.
// R3: R1 structure (uniform codebook row -> s_load; lane=row) with
//  - __launch_bounds__(256,6): 24 waves/CU, VGPR cap 80 (no spill; R2's
//    (512,8) cap of 64 caused scratch spills: WRITE_SIZE 4->26MB)
//  - z-row/code-row register-resident (R1 VGPR=28 => reloads)
//  - base-2 math end-to-end, W-accumulator removed from pass 1
//  - 2-way ILP in both sweeps; 4096/4096-block grids

#define N_E 16384
#define ED 32
#define T 8192
#define NSPLIT 32
#define NPER (N_E / NSPLIT)  // 512 codes per split (128 per wave-quarter)
#define QCODES (NPER / 4)    // 128
#define ROWS_B 64            // rows per k_p1 block
#define TCHUNK 64
#define TPER (T / TCHUNK)    // 128 rows per k_avg block

// fb = 200*log2(e)*dot + ses2[n] + a02[t]  (== fa/ln2, fa = -100*d)
#define K2 288.53900817779268f       // 200 * log2(e)
#define NS2 -144.26950408889634f     // -100 * log2(e)
#define LN2 0.6931471805599453f

__device__ __forceinline__ float fexp2(float x) { return __builtin_amdgcn_exp2f(x); }
__device__ __forceinline__ float flog2(float x) { return __builtin_amdgcn_logf(x); }

// identical fma order in both passes (lse consistency): u = streamed row
// (uniform -> SGPRs), r = register-resident per-lane vector.
__device__ __forceinline__ float dot32(const float4* __restrict__ u,
                                       const float4 r[8]) {
  float a0 = 0.f, a1 = 0.f, a2 = 0.f, a3 = 0.f;
#pragma unroll
  for (int j = 0; j < 2; ++j) {
    float4 q0 = u[4 * j + 0];
    a0 = fmaf(q0.x, r[4 * j + 0].x, a0); a0 = fmaf(q0.y, r[4 * j + 0].y, a0);
    a0 = fmaf(q0.z, r[4 * j + 0].z, a0); a0 = fmaf(q0.w, r[4 * j + 0].w, a0);
    float4 q1 = u[4 * j + 1];
    a1 = fmaf(q1.x, r[4 * j + 1].x, a1); a1 = fmaf(q1.y, r[4 * j + 1].y, a1);
    a1 = fmaf(q1.z, r[4 * j + 1].z, a1); a1 = fmaf(q1.w, r[4 * j + 1].w, a1);
    float4 q2 = u[4 * j + 2];
    a2 = fmaf(q2.x, r[4 * j + 2].x, a2); a2 = fmaf(q2.y, r[4 * j + 2].y, a2);
    a2 = fmaf(q2.z, r[4 * j + 2].z, a2); a2 = fmaf(q2.w, r[4 * j + 2].w, a2);
    float4 q3 = u[4 * j + 3];
    a3 = fmaf(q3.x, r[4 * j + 3].x, a3); a3 = fmaf(q3.y, r[4 * j + 3].y, a3);
    a3 = fmaf(q3.z, r[4 * j + 3].z, a3); a3 = fmaf(q3.w, r[4 * j + 3].w, a3);
  }
  return (a0 + a1) + (a2 + a3);
}

// --- K0: normalize embedding rows; ses2[n] = -100*log2e*sum(embn^2) ---
__global__ __launch_bounds__(256) void k_norm_emb(const float* __restrict__ emb,
    float* __restrict__ embn, float* __restrict__ ses2) {
  int n = blockIdx.x * 256 + threadIdx.x;
  const float* r = emb + (size_t)n * ED;
  float v[ED]; float s = 0.f;
#pragma unroll
  for (int k = 0; k < ED; ++k) { v[k] = r[k]; s = fmaf(v[k], v[k], s); }
  float inv = 1.0f / fmaxf(sqrtf(s), 1e-12f);
  float s2 = 0.f;
  float* o = embn + (size_t)n * ED;
#pragma unroll
  for (int k = 0; k < ED; ++k) { float w = v[k] * inv; o[k] = w; s2 = fmaf(w, w, s2); }
  ses2[n] = NS2 * s2;
}

// --- K1: transpose+normalize z -> zf (T x 32); a02[t] = -100*log2e*sum(zf^2) ---
__global__ __launch_bounds__(256) void k_norm_z(const float* __restrict__ z,
    float* __restrict__ zf, float* __restrict__ a02) {
  int t = blockIdx.x * 256 + threadIdx.x;
  int b = t >> 8, hw = t & 255;
  const float* base = z + (size_t)b * (ED * 256) + hw;
  float v[ED]; float s = 0.f;
#pragma unroll
  for (int k = 0; k < ED; ++k) { v[k] = base[k * 256]; s = fmaf(v[k], v[k], s); }
  float inv = 1.0f / fmaxf(sqrtf(s), 1e-12f);
  float s2 = 0.f;
  float* o = zf + (size_t)t * ED;
#pragma unroll
  for (int k = 0; k < ED; ++k) { float w = v[k] * inv; o[k] = w; s2 = fmaf(w, w, s2); }
  a02[t] = NS2 * s2;
}

// --- P1: block = 64 rows x one 512-code split; wave w sweeps code quarter.
//     Per lane: online base-2 softmax (m,Z) + argmax (first-index ties),
//     2-code ILP. Quarters merged in LDS -> pm/pZ/pidx[s*T+t]. ---
__global__ __launch_bounds__(256, 6) void k_p1(const float* __restrict__ embn,
    const float* __restrict__ ses2, const float* __restrict__ zf,
    const float* __restrict__ a02, float* __restrict__ pm,
    float* __restrict__ pZ, int* __restrict__ pidx) {
  const int lane = threadIdx.x & 63;
  const int w = threadIdx.x >> 6;
  const int t = blockIdx.x * ROWS_B + lane;
  const int s = blockIdx.y;
  const int nbase = s * NPER + w * QCODES;

  float4 zr[8];
  const float4* z4 = (const float4*)(zf + (size_t)t * ED);
#pragma unroll
  for (int k = 0; k < 8; ++k) zr[k] = z4[k];
  const float a2t = a02[t];

  float m0 = -1e30f, Z0 = 0.f, m1 = -1e30f, Z1 = 0.f;
  int b0 = nbase, b1 = nbase + 1;
  for (int i = 0; i < QCODES; i += 2) {
    const int n0 = nbase + i;
    const float4* e0 = (const float4*)(embn + (size_t)n0 * ED);
    const float4* e1 = e0 + 8;
    float d0 = dot32(e0, zr);
    float d1 = dot32(e1, zr);
    float fb0 = fmaf(K2, d0, a2t + ses2[n0]);
    float fb1 = fmaf(K2, d1, a2t + ses2[n0 + 1]);
    // online, branchless (strict > keeps earliest index on ties)
    float nm0 = fmaxf(m0, fb0);
    b0 = (fb0 > m0) ? n0 : b0;
    Z0 = fmaf(Z0, fexp2(m0 - nm0), fexp2(fb0 - nm0));
    m0 = nm0;
    float nm1 = fmaxf(m1, fb1);
    b1 = (fb1 > m1) ? (n0 + 1) : b1;
    Z1 = fmaf(Z1, fexp2(m1 - nm1), fexp2(fb1 - nm1));
    m1 = nm1;
  }
  // merge even/odd chains (equal -> lower n wins)
  float M = fmaxf(m0, m1);
  int bb = (m1 > m0) ? b1 : b0;
  if (m0 == m1) bb = min(b0, b1);
  float Zc = fmaf(Z0, fexp2(m0 - M), Z1 * fexp2(m1 - M));

  __shared__ float sm[4][ROWS_B], sZ[4][ROWS_B];
  __shared__ int sB[4][ROWS_B];
  sm[w][lane] = M; sZ[w][lane] = Zc; sB[w][lane] = bb;
  __syncthreads();
  if (threadIdx.x < ROWS_B) {
    const int r = threadIdx.x;
    float m = -1e30f; int bi = 0;
#pragma unroll
    for (int q = 0; q < 4; ++q) {  // ascending q == ascending n: strict >
      float mq = sm[q][r];
      if (mq > m) { m = mq; bi = sB[q][r]; }
    }
    float Z = 0.f;
#pragma unroll
    for (int q = 0; q < 4; ++q) Z = fmaf(sZ[q][r], fexp2(sm[q][r] - m), Z);
    const int p = s * T + blockIdx.x * ROWS_B + r;
    pm[p] = m; pZ[p] = Z; pidx[p] = bi;
  }
}

// --- K3: merge NSPLIT partials per row -> lse2[t], idx[t]; vq sum-of-squares. ---
__global__ __launch_bounds__(256) void k_merge(const float* __restrict__ pm,
    const float* __restrict__ pZ, const int* __restrict__ pidx,
    const float* __restrict__ zf, const float* __restrict__ embn,
    float* __restrict__ lse2, int* __restrict__ idxo, float* __restrict__ scal) {
  const int t = blockIdx.x * 256 + threadIdx.x;
  float m = -1e30f; int bi = 0;
  for (int s = 0; s < NSPLIT; ++s) {
    float ms = pm[s * T + t];
    if (ms > m) { m = ms; bi = pidx[s * T + t]; }  // strict >: lowest n on ties
  }
  float Z = 0.f;
  for (int s = 0; s < NSPLIT; ++s)
    Z = fmaf(pZ[s * T + t], fexp2(pm[s * T + t] - m), Z);
  lse2[t] = m + flog2(Z);  // log2(sum 2^fb)
  idxo[t] = bi;
  float ss = 0.f;
  const float* zq = embn + (size_t)bi * ED;
  const float* zr = zf + (size_t)t * ED;
#pragma unroll
  for (int k = 0; k < ED; ++k) { float df = zq[k] - zr[k]; ss = fmaf(df, df, ss); }
  __shared__ float red[256];
  red[threadIdx.x] = ss;
  __syncthreads();
  for (int st = 128; st > 0; st >>= 1) {
    if (threadIdx.x < st) red[threadIdx.x] += red[threadIdx.x + st];
    __syncthreads();
  }
  if (threadIdx.x == 0) atomicAdd(&scal[1], red[0]);
}

// --- P3: lane owns code n; sweep a t-chunk (uniform row -> s_load).
//     acc  = sum_t p        (avg_probs numerator)
//     acc2 = sum_t p*dl2    (sample entropy, base-2)  -- rare branch ---
__global__ __launch_bounds__(256, 6) void k_avg(const float* __restrict__ embn,
    const float* __restrict__ ses2, const float* __restrict__ zf,
    const float* __restrict__ a02, const float* __restrict__ lse2,
    float* __restrict__ avg, float* __restrict__ scal) {
  const int n = blockIdx.x * 256 + threadIdx.x;
  const int tb = blockIdx.y * TPER;

  float4 er[8];
  const float4* e4 = (const float4*)(embn + (size_t)n * ED);
#pragma unroll
  for (int k = 0; k < 8; ++k) er[k] = e4[k];
  const float s2n = ses2[n];

  float acc = 0.f, acc2 = 0.f;
  for (int i = 0; i < TPER; i += 2) {
    const int t0 = tb + i;
    const float4* zz0 = (const float4*)(zf + (size_t)t0 * ED);
    const float4* zz1 = zz0 + 8;
    float d0 = dot32(zz0, er);
    float d1 = dot32(zz1, er);
    float fb0 = fmaf(K2, d0, s2n + a02[t0]);
    float fb1 = fmaf(K2, d1, s2n + a02[t0 + 1]);
    float dl0 = fb0 - lse2[t0];
    float dl1 = fb1 - lse2[t0 + 1];
    if (dl0 > -110.f) {  // p >= 2^-110: everything else underflows in ref too
      float p = fexp2(dl0); acc += p; acc2 = fmaf(p, dl0, acc2);
    }
    if (dl1 > -110.f) {
      float p = fexp2(dl1); acc += p; acc2 = fmaf(p, dl1, acc2);
    }
  }
  atomicAdd(&avg[n], acc);
  __shared__ float red[256];
  red[threadIdx.x] = acc2;
  __syncthreads();
  for (int st = 128; st > 0; st >>= 1) {
    if (threadIdx.x < st) red[threadIdx.x] += red[threadIdx.x + st];
    __syncthreads();
  }
  if (threadIdx.x == 0) atomicAdd(&scal[0], red[0]);
}

// --- K4: straight-through output, back to (b,c,h,w). ---
__global__ __launch_bounds__(256) void k_out(const float* __restrict__ zf,
    const float* __restrict__ embn, const int* __restrict__ idxo,
    float* __restrict__ out) {
  int o = blockIdx.x * 256 + threadIdx.x;
  int c = (o >> 8) & 31;
  int t = ((o >> 13) << 8) | (o & 255);
  float zv = zf[(size_t)t * ED + c];
  float qv = embn[(size_t)idxo[t] * ED + c];
  out[o] = zv + (qv - zv);  // fp32 op order of zb + stopgrad(z_q - zb)
}

// --- K5: avg-entropy reduction + final scalars. ---
__global__ __launch_bounds__(256) void k_final(const float* __restrict__ avg,
    const float* __restrict__ scal, float* __restrict__ out) {
  float s = 0.f;
  for (int i = threadIdx.x; i < N_E; i += 256) {
    float a = avg[i] * (1.0f / T);
    s += a * (flog2(a + 1e-5f) * LN2);  // natural log; a==0 contributes ~0
  }
  __shared__ float red[256];
  red[threadIdx.x] = s;
  __syncthreads();
  for (int st = 128; st > 0; st >>= 1) {
    if (threadIdx.x < st) red[threadIdx.x] += red[threadIdx.x + st];
    __syncthreads();
  }
  if (threadIdx.x == 0) {
    float avg_entropy = -red[0];
    float sample_entropy = -(scal[0] * LN2) * (1.0f / T);  // base-2 -> nats
    float vq = scal[1] * (1.0f / (T * ED));
    out[T * ED + 0] = vq;
    out[T * ED + 1] = 0.25f * vq;
    out[T * ED + 2] = 0.1f * (sample_entropy - avg_entropy);
  }
}

extern "C" void kernel_launch(void* const* d_in, const int* in_sizes, int n_in,
                              void* d_out, int out_size, void* d_ws, size_t ws_size,
                              hipStream_t stream) {
  const float* z = (const float*)d_in[0];
  const float* emb = (const float*)d_in[1];
  float* out = (float*)d_out;
  float* w = (float*)d_ws;

  float* embn = w;                       // 524288
  float* ses2 = embn + 524288;           // 16384
  float* zf = ses2 + 16384;              // 262144
  float* a02 = zf + 262144;              // 8192
  float* pm = a02 + 8192;                // 262144
  float* pZ = pm + 262144;               // 262144
  int* pidx = (int*)(pZ + 262144);       // 262144
  float* lse2 = (float*)(pidx + 262144); // 8192
  int* idxo = (int*)(lse2 + 8192);       // 8192
  float* avg = (float*)(idxo + 8192);    // 16384
  float* scal = avg + 16384;             // 2    (~5.3 MB total)

  hipMemsetAsync(avg, 0, (16384 + 2) * sizeof(float), stream);

  k_norm_emb<<<64, 256, 0, stream>>>(emb, embn, ses2);
  k_norm_z<<<32, 256, 0, stream>>>(z, zf, a02);
  k_p1<<<dim3(T / ROWS_B, NSPLIT), 256, 0, stream>>>(embn, ses2, zf, a02, pm, pZ, pidx);
  k_merge<<<32, 256, 0, stream>>>(pm, pZ, pidx, zf, embn, lse2, idxo, scal);
  k_avg<<<dim3(N_E / 256, TCHUNK), 256, 0, stream>>>(embn, ses2, zf, a02, lse2, avg, scal);
  k_out<<<1024, 256, 0, stream>>>(zf, embn, idxo, out);
  k_final<<<1, 256, 0, stream>>>(avg, scal, out);
}

// Round 4
// 461.704 us; speedup vs baseline: 5.1754x; 5.1754x over previous
//
#include <hip/hip_runtime.h>

// VQ-VAE vector quantize + losses, MI355X fp32.
// T=8192 rows (b*h*w), N_E=16384 codes, D=32.
// R4: R1 structure (workgroup-uniform codebook sweep -> s_load into SGPRs;
//     lane = row) with:
//  - per-lane row vector in NAMED float4 vars, pinned once via asm
//    (R3's array-param decay put it in scratch: FETCH 6.8GB, WRITE 244MB)
//  - NO per-wave code split (R3's threadIdx-derived nbase killed
//    scalarization: SGPR 96->32)
//  - occupancy via more blocks: NSPLIT=64 / TCH=32 -> 2048-block grids
//  - base-2 softmax, no W accumulator in pass 1, 2-code ILP

#define N_E 16384
#define ED 32
#define T 8192
#define NSPLIT 64
#define NPER (N_E / NSPLIT)  // 256 codes per split
#define TCH 32
#define TPER (T / TCH)       // 256 rows per k_avg chunk

// fb = 200*log2(e)*dot + ses2[n] + a02[t]  (== fa/ln2, fa = -100*d)
#define K2 288.53900817779268f       // 200 * log2(e)
#define NS2 -144.26950408889634f     // -100 * log2(e)
#define LN2 0.6931471805599453f

__device__ __forceinline__ float fexp2(float x) { return __builtin_amdgcn_exp2f(x); }
__device__ __forceinline__ float flog2(float x) { return __builtin_amdgcn_logf(x); }

#define PIN4(q) asm volatile("" : "+v"((q).x), "+v"((q).y), "+v"((q).z), "+v"((q).w))

// dot of streamed (uniform -> SGPR) row EP[0..7] with resident r0..r7.
#define DOT_R(EP, OUT) do {                                                  \
    float A0 = 0.f, A1 = 0.f, A2 = 0.f, A3 = 0.f; float4 q;                  \
    q = (EP)[0]; A0 = fmaf(q.x, r0.x, A0); A0 = fmaf(q.y, r0.y, A0);         \
                 A0 = fmaf(q.z, r0.z, A0); A0 = fmaf(q.w, r0.w, A0);         \
    q = (EP)[1]; A1 = fmaf(q.x, r1.x, A1); A1 = fmaf(q.y, r1.y, A1);         \
                 A1 = fmaf(q.z, r1.z, A1); A1 = fmaf(q.w, r1.w, A1);         \
    q = (EP)[2]; A2 = fmaf(q.x, r2.x, A2); A2 = fmaf(q.y, r2.y, A2);         \
                 A2 = fmaf(q.z, r2.z, A2); A2 = fmaf(q.w, r2.w, A2);         \
    q = (EP)[3]; A3 = fmaf(q.x, r3.x, A3); A3 = fmaf(q.y, r3.y, A3);         \
                 A3 = fmaf(q.z, r3.z, A3); A3 = fmaf(q.w, r3.w, A3);         \
    q = (EP)[4]; A0 = fmaf(q.x, r4.x, A0); A0 = fmaf(q.y, r4.y, A0);         \
                 A0 = fmaf(q.z, r4.z, A0); A0 = fmaf(q.w, r4.w, A0);         \
    q = (EP)[5]; A1 = fmaf(q.x, r5.x, A1); A1 = fmaf(q.y, r5.y, A1);         \
                 A1 = fmaf(q.z, r5.z, A1); A1 = fmaf(q.w, r5.w, A1);         \
    q = (EP)[6]; A2 = fmaf(q.x, r6.x, A2); A2 = fmaf(q.y, r6.y, A2);         \
                 A2 = fmaf(q.z, r6.z, A2); A2 = fmaf(q.w, r6.w, A2);         \
    q = (EP)[7]; A3 = fmaf(q.x, r7.x, A3); A3 = fmaf(q.y, r7.y, A3);         \
                 A3 = fmaf(q.z, r7.z, A3); A3 = fmaf(q.w, r7.w, A3);         \
    OUT = (A0 + A1) + (A2 + A3);                                             \
  } while (0)

// --- K0: normalize embedding rows; ses2[n] = -100*log2e*sum(embn^2) ---
__global__ __launch_bounds__(256) void k_norm_emb(const float* __restrict__ emb,
    float* __restrict__ embn, float* __restrict__ ses2) {
  int n = blockIdx.x * 256 + threadIdx.x;
  const float* r = emb + (size_t)n * ED;
  float v[ED]; float s = 0.f;
#pragma unroll
  for (int k = 0; k < ED; ++k) { v[k] = r[k]; s = fmaf(v[k], v[k], s); }
  float inv = 1.0f / fmaxf(sqrtf(s), 1e-12f);
  float s2 = 0.f;
  float* o = embn + (size_t)n * ED;
#pragma unroll
  for (int k = 0; k < ED; ++k) { float w = v[k] * inv; o[k] = w; s2 = fmaf(w, w, s2); }
  ses2[n] = NS2 * s2;
}

// --- K1: transpose+normalize z -> zf (T x 32); a02[t] = -100*log2e*sum(zf^2) ---
__global__ __launch_bounds__(256) void k_norm_z(const float* __restrict__ z,
    float* __restrict__ zf, float* __restrict__ a02) {
  int t = blockIdx.x * 256 + threadIdx.x;
  int b = t >> 8, hw = t & 255;
  const float* base = z + (size_t)b * (ED * 256) + hw;
  float v[ED]; float s = 0.f;
#pragma unroll
  for (int k = 0; k < ED; ++k) { v[k] = base[k * 256]; s = fmaf(v[k], v[k], s); }
  float inv = 1.0f / fmaxf(sqrtf(s), 1e-12f);
  float s2 = 0.f;
  float* o = zf + (size_t)t * ED;
#pragma unroll
  for (int k = 0; k < ED; ++k) { float w = v[k] * inv; o[k] = w; s2 = fmaf(w, w, s2); }
  a02[t] = NS2 * s2;
}

// --- P1: lane owns row t; whole block sweeps one 256-code split (uniform
//     addresses -> s_load). Online base-2 softmax (m,Z) + argmax
//     (first-index ties), 2-code ILP. ---
__global__ __launch_bounds__(256) void k_p1(const float* __restrict__ embn,
    const float* __restrict__ ses2, const float* __restrict__ zf,
    const float* __restrict__ a02, float* __restrict__ pm,
    float* __restrict__ pZ, int* __restrict__ pidx) {
  const int t = blockIdx.x * 256 + threadIdx.x;
  const int s = blockIdx.y;
  const int nbase = s * NPER;

  const float4* z4 = (const float4*)(zf + (size_t)t * ED);
  float4 r0 = z4[0], r1 = z4[1], r2 = z4[2], r3 = z4[3];
  float4 r4 = z4[4], r5 = z4[5], r6 = z4[6], r7 = z4[7];
  PIN4(r0); PIN4(r1); PIN4(r2); PIN4(r3);
  PIN4(r4); PIN4(r5); PIN4(r6); PIN4(r7);
  const float a2t = a02[t];

  float m0 = -1e30f, Z0 = 0.f, m1 = -1e30f, Z1 = 0.f;
  int b0 = nbase, b1 = nbase + 1;
  for (int i = 0; i < NPER; i += 2) {
    const int n0 = nbase + i;
    const float4* e0 = (const float4*)(embn) + (size_t)n0 * 8;
    const float4* e1 = e0 + 8;
    float d0, d1;
    DOT_R(e0, d0);
    DOT_R(e1, d1);
    float fb0 = fmaf(K2, d0, a2t + ses2[n0]);
    float fb1 = fmaf(K2, d1, a2t + ses2[n0 + 1]);
    // online, branchless (strict > keeps earliest index on ties)
    float nm0 = fmaxf(m0, fb0);
    b0 = (fb0 > m0) ? n0 : b0;
    Z0 = fmaf(Z0, fexp2(m0 - nm0), fexp2(fb0 - nm0));
    m0 = nm0;
    float nm1 = fmaxf(m1, fb1);
    b1 = (fb1 > m1) ? (n0 + 1) : b1;
    Z1 = fmaf(Z1, fexp2(m1 - nm1), fexp2(fb1 - nm1));
    m1 = nm1;
  }
  // merge even/odd chains (equal -> lower n wins)
  float M = fmaxf(m0, m1);
  int bb = (m1 > m0) ? b1 : b0;
  if (m0 == m1) bb = min(b0, b1);
  float Zc = fmaf(Z0, fexp2(m0 - M), Z1 * fexp2(m1 - M));

  const int p = s * T + t;
  pm[p] = M; pZ[p] = Zc; pidx[p] = bb;
}

// --- K3: merge NSPLIT partials per row -> lse2[t], idx[t]; vq sum-of-squares. ---
__global__ __launch_bounds__(256) void k_merge(const float* __restrict__ pm,
    const float* __restrict__ pZ, const int* __restrict__ pidx,
    const float* __restrict__ zf, const float* __restrict__ embn,
    float* __restrict__ lse2, int* __restrict__ idxo, float* __restrict__ scal) {
  const int t = blockIdx.x * 256 + threadIdx.x;
  float m = -1e30f; int bi = 0;
  for (int s = 0; s < NSPLIT; ++s) {
    float ms = pm[s * T + t];
    if (ms > m) { m = ms; bi = pidx[s * T + t]; }  // strict >: lowest n on ties
  }
  float Z = 0.f;
  for (int s = 0; s < NSPLIT; ++s)
    Z = fmaf(pZ[s * T + t], fexp2(pm[s * T + t] - m), Z);
  lse2[t] = m + flog2(Z);  // log2(sum 2^fb)
  idxo[t] = bi;
  float ss = 0.f;
  const float* zq = embn + (size_t)bi * ED;
  const float* zr = zf + (size_t)t * ED;
#pragma unroll
  for (int k = 0; k < ED; ++k) { float df = zq[k] - zr[k]; ss = fmaf(df, df, ss); }
  __shared__ float red[256];
  red[threadIdx.x] = ss;
  __syncthreads();
  for (int st = 128; st > 0; st >>= 1) {
    if (threadIdx.x < st) red[threadIdx.x] += red[threadIdx.x + st];
    __syncthreads();
  }
  if (threadIdx.x == 0) atomicAdd(&scal[1], red[0]);
}

// --- P3: lane owns code n; whole block sweeps one 256-row chunk (uniform
//     addresses -> s_load).  acc = sum_t p ; acc2 = sum_t p*dl2 (base-2,
//     sample entropy) in a mostly-dead branch (softmax temp 0.01 is peaked). ---
__global__ __launch_bounds__(256) void k_avg(const float* __restrict__ embn,
    const float* __restrict__ ses2, const float* __restrict__ zf,
    const float* __restrict__ a02, const float* __restrict__ lse2,
    float* __restrict__ avg, float* __restrict__ scal) {
  const int n = blockIdx.x * 256 + threadIdx.x;
  const int tb = blockIdx.y * TPER;

  const float4* e4 = (const float4*)(embn + (size_t)n * ED);
  float4 r0 = e4[0], r1 = e4[1], r2 = e4[2], r3 = e4[3];
  float4 r4 = e4[4], r5 = e4[5], r6 = e4[6], r7 = e4[7];
  PIN4(r0); PIN4(r1); PIN4(r2); PIN4(r3);
  PIN4(r4); PIN4(r5); PIN4(r6); PIN4(r7);
  const float s2n = ses2[n];

  float acc = 0.f, acc2 = 0.f;
  for (int i = 0; i < TPER; i += 2) {
    const int t0 = tb + i;
    const float4* zz0 = (const float4*)(zf) + (size_t)t0 * 8;
    const float4* zz1 = zz0 + 8;
    float d0, d1;
    DOT_R(zz0, d0);
    DOT_R(zz1, d1);
    float fb0 = fmaf(K2, d0, s2n + a02[t0]);
    float fb1 = fmaf(K2, d1, s2n + a02[t0 + 1]);
    float dl0 = fb0 - lse2[t0];
    float dl1 = fb1 - lse2[t0 + 1];
    if (dl0 > -110.f) {  // p >= 2^-110: everything smaller underflows in ref too
      float p = fexp2(dl0); acc += p; acc2 = fmaf(p, dl0, acc2);
    }
    if (dl1 > -110.f) {
      float p = fexp2(dl1); acc += p; acc2 = fmaf(p, dl1, acc2);
    }
  }
  atomicAdd(&avg[n], acc);
  __shared__ float red[256];
  red[threadIdx.x] = acc2;
  __syncthreads();
  for (int st = 128; st > 0; st >>= 1) {
    if (threadIdx.x < st) red[threadIdx.x] += red[threadIdx.x + st];
    __syncthreads();
  }
  if (threadIdx.x == 0) atomicAdd(&scal[0], red[0]);
}

// --- K4: straight-through output, back to (b,c,h,w). ---
__global__ __launch_bounds__(256) void k_out(const float* __restrict__ zf,
    const float* __restrict__ embn, const int* __restrict__ idxo,
    float* __restrict__ out) {
  int o = blockIdx.x * 256 + threadIdx.x;
  int c = (o >> 8) & 31;
  int t = ((o >> 13) << 8) | (o & 255);
  float zv = zf[(size_t)t * ED + c];
  float qv = embn[(size_t)idxo[t] * ED + c];
  out[o] = zv + (qv - zv);  // fp32 op order of zb + stopgrad(z_q - zb)
}

// --- K5: avg-entropy reduction + final scalars. ---
__global__ __launch_bounds__(256) void k_final(const float* __restrict__ avg,
    const float* __restrict__ scal, float* __restrict__ out) {
  float s = 0.f;
  for (int i = threadIdx.x; i < N_E; i += 256) {
    float a = avg[i] * (1.0f / T);
    s += a * (flog2(a + 1e-5f) * LN2);  // natural log; a==0 contributes ~0
  }
  __shared__ float red[256];
  red[threadIdx.x] = s;
  __syncthreads();
  for (int st = 128; st > 0; st >>= 1) {
    if (threadIdx.x < st) red[threadIdx.x] += red[threadIdx.x + st];
    __syncthreads();
  }
  if (threadIdx.x == 0) {
    float avg_entropy = -red[0];
    float sample_entropy = -(scal[0] * LN2) * (1.0f / T);  // base-2 -> nats
    float vq = scal[1] * (1.0f / (T * ED));
    out[T * ED + 0] = vq;
    out[T * ED + 1] = 0.25f * vq;
    out[T * ED + 2] = 0.1f * (sample_entropy - avg_entropy);
  }
}

extern "C" void kernel_launch(void* const* d_in, const int* in_sizes, int n_in,
                              void* d_out, int out_size, void* d_ws, size_t ws_size,
                              hipStream_t stream) {
  const float* z = (const float*)d_in[0];
  const float* emb = (const float*)d_in[1];
  float* out = (float*)d_out;
  float* w = (float*)d_ws;

  float* embn = w;                       // 524288
  float* ses2 = embn + 524288;           // 16384
  float* zf = ses2 + 16384;              // 262144
  float* a02 = zf + 262144;              // 8192
  float* pm = a02 + 8192;                // 524288 (NSPLIT*T)
  float* pZ = pm + 524288;               // 524288
  int* pidx = (int*)(pZ + 524288);       // 524288
  float* lse2 = (float*)(pidx + 524288); // 8192
  int* idxo = (int*)(lse2 + 8192);       // 8192
  float* avg = (float*)(idxo + 8192);    // 16384
  float* scal = avg + 16384;             // 2    (~9.5 MB total)

  hipMemsetAsync(avg, 0, (16384 + 2) * sizeof(float), stream);

  k_norm_emb<<<64, 256, 0, stream>>>(emb, embn, ses2);
  k_norm_z<<<32, 256, 0, stream>>>(z, zf, a02);
  k_p1<<<dim3(T / 256, NSPLIT), 256, 0, stream>>>(embn, ses2, zf, a02, pm, pZ, pidx);
  k_merge<<<32, 256, 0, stream>>>(pm, pZ, pidx, zf, embn, lse2, idxo, scal);
  k_avg<<<dim3(N_E / 256, TCH), 256, 0, stream>>>(embn, ses2, zf, a02, lse2, avg, scal);
  k_out<<<1024, 256, 0, stream>>>(zf, embn, idxo, out);
  k_final<<<1, 256, 0, stream>>>(avg, scal, out);
}

// Round 5
// 240.815 us; speedup vs baseline: 9.9226x; 1.9173x over previous
//
#include <hip/hip_runtime.h>

// VQ-VAE vector quantize + losses, MI355X.
// T=8192 rows, N_E=16384 codes, D=32.
// R5: distance matmul moved to MFMA via bf16 hi/lo split (3x
//     mfma_f32_16x16x32_bf16, fp32 acc). Pass 1: top-2 + biased-exp softmax
//     (no online max). k_merge: exact fp32 re-compare of the two candidates
//     (protects argmin against the ~4e-3 fb error). Pass 2: transposed twin
//     for avg_probs + sample entropy. No LDS staging; B-frags stream from L2.

#define N_E 16384
#define ED 32
#define T 8192
#define NS1 16      // pass-1 code splits (1024 codes each)
#define RS2 8       // pass-2 row splits  (1024 rows each)

#define K2 288.53900817779268f    // 200 * log2(e)
#define NS2F -144.26950408889634f // -100 * log2(e)
#define LN2 0.6931471805599453f

typedef __attribute__((ext_vector_type(8))) short s16x8;
typedef __attribute__((ext_vector_type(4))) float f32x4;

__device__ __forceinline__ float fexp2(float x) { return __builtin_amdgcn_exp2f(x); }
__device__ __forceinline__ float flog2(float x) { return __builtin_amdgcn_logf(x); }

__device__ __forceinline__ unsigned short f2bf(float x) {
  unsigned u = __float_as_uint(x);
  unsigned r = (u + 0x7FFFu + ((u >> 16) & 1u)) >> 16;
  return (unsigned short)r;
}
__device__ __forceinline__ float bf2f(unsigned short h) {
  return __uint_as_float(((unsigned)h) << 16);
}

// exact fp32 dot of a streamed row with 8 resident float4s (by value: no
// addressable array -> no scratch; R3's array-param decay lesson)
__device__ __forceinline__ float dot32x(const float* __restrict__ p,
    float4 z0, float4 z1, float4 z2, float4 z3,
    float4 z4, float4 z5, float4 z6, float4 z7) {
  const float4* e = (const float4*)p;
  float a0 = 0.f, a1 = 0.f, a2 = 0.f, a3 = 0.f; float4 q;
  q = e[0]; a0 = fmaf(q.x, z0.x, a0); a0 = fmaf(q.y, z0.y, a0);
            a0 = fmaf(q.z, z0.z, a0); a0 = fmaf(q.w, z0.w, a0);
  q = e[1]; a1 = fmaf(q.x, z1.x, a1); a1 = fmaf(q.y, z1.y, a1);
            a1 = fmaf(q.z, z1.z, a1); a1 = fmaf(q.w, z1.w, a1);
  q = e[2]; a2 = fmaf(q.x, z2.x, a2); a2 = fmaf(q.y, z2.y, a2);
            a2 = fmaf(q.z, z2.z, a2); a2 = fmaf(q.w, z2.w, a2);
  q = e[3]; a3 = fmaf(q.x, z3.x, a3); a3 = fmaf(q.y, z3.y, a3);
            a3 = fmaf(q.z, z3.z, a3); a3 = fmaf(q.w, z3.w, a3);
  q = e[4]; a0 = fmaf(q.x, z4.x, a0); a0 = fmaf(q.y, z4.y, a0);
            a0 = fmaf(q.z, z4.z, a0); a0 = fmaf(q.w, z4.w, a0);
  q = e[5]; a1 = fmaf(q.x, z5.x, a1); a1 = fmaf(q.y, z5.y, a1);
            a1 = fmaf(q.z, z5.z, a1); a1 = fmaf(q.w, z5.w, a1);
  q = e[6]; a2 = fmaf(q.x, z6.x, a2); a2 = fmaf(q.y, z6.y, a2);
            a2 = fmaf(q.z, z6.z, a2); a2 = fmaf(q.w, z6.w, a2);
  q = e[7]; a3 = fmaf(q.x, z7.x, a3); a3 = fmaf(q.y, z7.y, a3);
            a3 = fmaf(q.z, z7.z, a3); a3 = fmaf(q.w, z7.w, a3);
  return (a0 + a1) + (a2 + a3);
}

// --- prep: normalize embedding rows; fp32 + bf16 hi/lo + ses2 (fb units) ---
__global__ __launch_bounds__(256) void k_prep_emb(const float* __restrict__ emb,
    float* __restrict__ embn, float* __restrict__ ses2,
    short* __restrict__ ehi, short* __restrict__ elo) {
  int n = blockIdx.x * 256 + threadIdx.x;
  const float4* r4 = (const float4*)(emb + (size_t)n * ED);
  float4 v[8]; float s = 0.f;
#pragma unroll
  for (int j = 0; j < 8; ++j) {
    v[j] = r4[j];
    s = fmaf(v[j].x, v[j].x, s); s = fmaf(v[j].y, v[j].y, s);
    s = fmaf(v[j].z, v[j].z, s); s = fmaf(v[j].w, v[j].w, s);
  }
  float inv = 1.0f / fmaxf(sqrtf(s), 1e-12f);
  float s2 = 0.f;
  float4* o4 = (float4*)(embn + (size_t)n * ED);
#pragma unroll
  for (int j = 0; j < 8; ++j) {
    float4 w; w.x = v[j].x * inv; w.y = v[j].y * inv;
    w.z = v[j].z * inv; w.w = v[j].w * inv;
    o4[j] = w; v[j] = w;
    s2 = fmaf(w.x, w.x, s2); s2 = fmaf(w.y, w.y, s2);
    s2 = fmaf(w.z, w.z, s2); s2 = fmaf(w.w, w.w, s2);
  }
  ses2[n] = NS2F * s2;
  s16x8* h8 = (s16x8*)(ehi + (size_t)n * ED);
  s16x8* l8 = (s16x8*)(elo + (size_t)n * ED);
#pragma unroll
  for (int j = 0; j < 4; ++j) {
    float f[8] = { v[2*j].x, v[2*j].y, v[2*j].z, v[2*j].w,
                   v[2*j+1].x, v[2*j+1].y, v[2*j+1].z, v[2*j+1].w };
    s16x8 H, L;
#pragma unroll
    for (int e = 0; e < 8; ++e) {
      unsigned short h = f2bf(f[e]);
      H[e] = (short)h;
      L[e] = (short)f2bf(f[e] - bf2f(h));
    }
    h8[j] = H; l8[j] = L;
  }
}

// --- prep: transpose+normalize z; fp32 zf + bf16 hi/lo + a02 (fb units) ---
__global__ __launch_bounds__(256) void k_prep_z(const float* __restrict__ z,
    float* __restrict__ zf, float* __restrict__ a02,
    short* __restrict__ zhi, short* __restrict__ zlo) {
  int t = blockIdx.x * 256 + threadIdx.x;
  int b = t >> 8, hw = t & 255;
  const float* base = z + (size_t)b * (ED * 256) + hw;
  float4 v[8]; float s = 0.f;
#pragma unroll
  for (int j = 0; j < 8; ++j) {
    float4 w;
    w.x = base[(4*j+0) * 256]; w.y = base[(4*j+1) * 256];
    w.z = base[(4*j+2) * 256]; w.w = base[(4*j+3) * 256];
    v[j] = w;
    s = fmaf(w.x, w.x, s); s = fmaf(w.y, w.y, s);
    s = fmaf(w.z, w.z, s); s = fmaf(w.w, w.w, s);
  }
  float inv = 1.0f / fmaxf(sqrtf(s), 1e-12f);
  float s2 = 0.f;
  float4* o4 = (float4*)(zf + (size_t)t * ED);
#pragma unroll
  for (int j = 0; j < 8; ++j) {
    float4 w; w.x = v[j].x * inv; w.y = v[j].y * inv;
    w.z = v[j].z * inv; w.w = v[j].w * inv;
    o4[j] = w; v[j] = w;
    s2 = fmaf(w.x, w.x, s2); s2 = fmaf(w.y, w.y, s2);
    s2 = fmaf(w.z, w.z, s2); s2 = fmaf(w.w, w.w, s2);
  }
  a02[t] = NS2F * s2;
  s16x8* h8 = (s16x8*)(zhi + (size_t)t * ED);
  s16x8* l8 = (s16x8*)(zlo + (size_t)t * ED);
#pragma unroll
  for (int j = 0; j < 4; ++j) {
    float f[8] = { v[2*j].x, v[2*j].y, v[2*j].z, v[2*j].w,
                   v[2*j+1].x, v[2*j+1].y, v[2*j+1].z, v[2*j+1].w };
    s16x8 H, L;
#pragma unroll
    for (int e = 0; e < 8; ++e) {
      unsigned short h = f2bf(f[e]);
      H[e] = (short)h;
      L[e] = (short)f2bf(f[e] - bf2f(h));
    }
    h8[j] = H; l8[j] = L;
  }
}

// --- pass 1: wave owns 32 rows (2 groups x 16), sweeps a 1024-code split
//     in 16x16x32 MFMA tiles; per (lane, group, reg) slot: top-2 (m,i) and
//     biased Z = sum 2^(fb+80). Cross-lane (16 cols) reduce, write partials. ---
__global__ __launch_bounds__(256) void k_pass1(
    const short* __restrict__ eh, const short* __restrict__ el,
    const short* __restrict__ zh, const short* __restrict__ zl,
    const float* __restrict__ ses2, const float* __restrict__ a02,
    float* __restrict__ pm1, float* __restrict__ pm2, float* __restrict__ pZ,
    int* __restrict__ pi1, int* __restrict__ pi2) {
  const int lane = threadIdx.x & 63, wv = threadIdx.x >> 6;
  const int q = lane >> 4, c = lane & 15;
  const int rowbase = blockIdx.x * 128 + wv * 32;
  const int nb0 = blockIdx.y * (N_E / NS1);

  s16x8 ah0 = *(const s16x8*)(zh + (size_t)(rowbase + c) * ED + q * 8);
  s16x8 al0 = *(const s16x8*)(zl + (size_t)(rowbase + c) * ED + q * 8);
  s16x8 ah1 = *(const s16x8*)(zh + (size_t)(rowbase + 16 + c) * ED + q * 8);
  s16x8 al1 = *(const s16x8*)(zl + (size_t)(rowbase + 16 + c) * ED + q * 8);

  float ar[8];
#pragma unroll
  for (int g = 0; g < 2; ++g)
#pragma unroll
    for (int r = 0; r < 4; ++r)
      ar[g * 4 + r] = a02[rowbase + g * 16 + q * 4 + r] + 80.0f;

  float m1[8], m2[8], Zs[8]; int i1[8], i2[8];
#pragma unroll
  for (int k = 0; k < 8; ++k) {
    m1[k] = -1e30f; m2[k] = -1e30f; Zs[k] = 0.f;
    i1[k] = nb0 + c; i2[k] = nb0 + c;
  }

  for (int tile = 0; tile < (N_E / NS1) / 16; ++tile) {
    const int nb = nb0 + tile * 16;
    s16x8 bh = *(const s16x8*)(eh + (size_t)(nb + c) * ED + q * 8);
    s16x8 bl = *(const s16x8*)(el + (size_t)(nb + c) * ED + q * 8);
    float sesc = ses2[nb + c];
    f32x4 acc0 = {0.f, 0.f, 0.f, 0.f}, acc1 = {0.f, 0.f, 0.f, 0.f};
    acc0 = __builtin_amdgcn_mfma_f32_16x16x32_bf16(ah0, bh, acc0, 0, 0, 0);
    acc1 = __builtin_amdgcn_mfma_f32_16x16x32_bf16(ah1, bh, acc1, 0, 0, 0);
    acc0 = __builtin_amdgcn_mfma_f32_16x16x32_bf16(al0, bh, acc0, 0, 0, 0);
    acc1 = __builtin_amdgcn_mfma_f32_16x16x32_bf16(al1, bh, acc1, 0, 0, 0);
    acc0 = __builtin_amdgcn_mfma_f32_16x16x32_bf16(ah0, bl, acc0, 0, 0, 0);
    acc1 = __builtin_amdgcn_mfma_f32_16x16x32_bf16(ah1, bl, acc1, 0, 0, 0);
    const int vn = nb + c;
#pragma unroll
    for (int g = 0; g < 2; ++g) {
#pragma unroll
      for (int r = 0; r < 4; ++r) {
        const int k = g * 4 + r;
        float v = (g == 0) ? acc0[r] : acc1[r];
        float fb = fmaf(K2, v, ar[k] + sesc);
        bool g1 = fb > m1[k];
        bool g2 = fb > m2[k];
        i2[k] = g1 ? i1[k] : (g2 ? vn : i2[k]);
        m2[k] = g1 ? m1[k] : fmaxf(m2[k], fb);
        i1[k] = g1 ? vn : i1[k];
        m1[k] = fmaxf(m1[k], fb);
        Zs[k] += fexp2(fb);
      }
    }
  }

  // reduce across the 16 cols within each quad
#pragma unroll
  for (int d = 1; d < 16; d <<= 1) {
#pragma unroll
    for (int k = 0; k < 8; ++k) {
      float om1 = __shfl_xor(m1[k], d);
      float om2 = __shfl_xor(m2[k], d);
      float oZ = __shfl_xor(Zs[k], d);
      int oi1 = __shfl_xor(i1[k], d);
      int oi2 = __shfl_xor(i2[k], d);
      bool c1 = om1 > m1[k];
      float lm = c1 ? m1[k] : om1;  // loser of m1 duel
      int li = c1 ? i1[k] : oi1;
      float nm1 = c1 ? om1 : m1[k];
      int ni1 = c1 ? oi1 : i1[k];
      bool cb = om2 > m2[k];
      float mm2 = cb ? om2 : m2[k];
      int mi2 = cb ? oi2 : i2[k];
      bool c3 = mm2 > lm;
      m1[k] = nm1; i1[k] = ni1;
      m2[k] = c3 ? mm2 : lm;
      i2[k] = c3 ? mi2 : li;
      Zs[k] += oZ;
    }
  }

#pragma unroll
  for (int k = 0; k < 8; ++k) {   // unrolled: no runtime-indexed array access
    if (c == k) {
      const int g = k >> 2, r = k & 3;
      const int t = rowbase + g * 16 + q * 4 + r;
      const int p = blockIdx.y * T + t;
      pm1[p] = m1[k]; pm2[p] = m2[k]; pZ[p] = Zs[k];
      pi1[p] = i1[k]; pi2[p] = i2[k];
    }
  }
}

// --- merge: combine NS1 split partials per row; exact fp32 re-compare of the
//     two candidates; lse2, c2 = a02 - lse2, vq sum-of-squares. ---
__global__ __launch_bounds__(256) void k_merge(
    const float* __restrict__ pm1, const float* __restrict__ pm2,
    const float* __restrict__ pZ, const int* __restrict__ pi1,
    const int* __restrict__ pi2, const float* __restrict__ zf,
    const float* __restrict__ embn, const float* __restrict__ ses2,
    const float* __restrict__ a02, float* __restrict__ c2,
    int* __restrict__ idxo, float* __restrict__ scal) {
  const int t = blockIdx.x * 256 + threadIdx.x;
  float m1 = -1e30f, m2 = -1e30f, Z = 0.f;
  int i1 = 0, i2 = 0;
  for (int s = 0; s < NS1; ++s) {
    const int p = s * T + t;
    float sm1 = pm1[p], sm2 = pm2[p];
    int si1 = pi1[p], si2 = pi2[p];
    Z += pZ[p];
    bool c1 = sm1 > m1;
    float lm = c1 ? m1 : sm1;
    int li = c1 ? i1 : si1;
    float nm1 = c1 ? sm1 : m1;
    int ni1 = c1 ? si1 : i1;
    bool cb = sm2 > m2;
    float mm2 = cb ? sm2 : m2;
    int mi2 = cb ? si2 : i2;
    bool c3 = mm2 > lm;
    m1 = nm1; i1 = ni1;
    m2 = c3 ? mm2 : lm;
    i2 = c3 ? mi2 : li;
  }
  const float a02t = a02[t];
  const float lse2 = flog2(Z) - 80.0f;
  c2[t] = a02t - lse2;

  // exact fp32 refine between i1, i2 (reference rule: larger fa, tie->lower n)
  const float4* zr4 = (const float4*)(zf + (size_t)t * ED);
  float4 z0 = zr4[0], z1 = zr4[1], z2 = zr4[2], z3 = zr4[3];
  float4 z4 = zr4[4], z5 = zr4[5], z6 = zr4[6], z7 = zr4[7];
  float d1 = dot32x(embn + (size_t)i1 * ED, z0, z1, z2, z3, z4, z5, z6, z7);
  float d2 = dot32x(embn + (size_t)i2 * ED, z0, z1, z2, z3, z4, z5, z6, z7);
  float fb1 = fmaf(K2, d1, a02t + ses2[i1]);
  float fb2 = fmaf(K2, d2, a02t + ses2[i2]);
  int bi = (fb2 > fb1 || (fb2 == fb1 && i2 < i1)) ? i2 : i1;
  idxo[t] = bi;

  float ss = 0.f;
  const float4* e4 = (const float4*)(embn + (size_t)bi * ED);
  {
    float4 q; float df;
    q = e4[0]; df = q.x-z0.x; ss = fmaf(df,df,ss); df = q.y-z0.y; ss = fmaf(df,df,ss);
               df = q.z-z0.z; ss = fmaf(df,df,ss); df = q.w-z0.w; ss = fmaf(df,df,ss);
    q = e4[1]; df = q.x-z1.x; ss = fmaf(df,df,ss); df = q.y-z1.y; ss = fmaf(df,df,ss);
               df = q.z-z1.z; ss = fmaf(df,df,ss); df = q.w-z1.w; ss = fmaf(df,df,ss);
    q = e4[2]; df = q.x-z2.x; ss = fmaf(df,df,ss); df = q.y-z2.y; ss = fmaf(df,df,ss);
               df = q.z-z2.z; ss = fmaf(df,df,ss); df = q.w-z2.w; ss = fmaf(df,df,ss);
    q = e4[3]; df = q.x-z3.x; ss = fmaf(df,df,ss); df = q.y-z3.y; ss = fmaf(df,df,ss);
               df = q.z-z3.z; ss = fmaf(df,df,ss); df = q.w-z3.w; ss = fmaf(df,df,ss);
    q = e4[4]; df = q.x-z4.x; ss = fmaf(df,df,ss); df = q.y-z4.y; ss = fmaf(df,df,ss);
               df = q.z-z4.z; ss = fmaf(df,df,ss); df = q.w-z4.w; ss = fmaf(df,df,ss);
    q = e4[5]; df = q.x-z5.x; ss = fmaf(df,df,ss); df = q.y-z5.y; ss = fmaf(df,df,ss);
               df = q.z-z5.z; ss = fmaf(df,df,ss); df = q.w-z5.w; ss = fmaf(df,df,ss);
    q = e4[6]; df = q.x-z6.x; ss = fmaf(df,df,ss); df = q.y-z6.y; ss = fmaf(df,df,ss);
               df = q.z-z6.z; ss = fmaf(df,df,ss); df = q.w-z6.w; ss = fmaf(df,df,ss);
    q = e4[7]; df = q.x-z7.x; ss = fmaf(df,df,ss); df = q.y-z7.y; ss = fmaf(df,df,ss);
               df = q.z-z7.z; ss = fmaf(df,df,ss); df = q.w-z7.w; ss = fmaf(df,df,ss);
  }
  __shared__ float red[256];
  red[threadIdx.x] = ss;
  __syncthreads();
  for (int st = 128; st > 0; st >>= 1) {
    if (threadIdx.x < st) red[threadIdx.x] += red[threadIdx.x + st];
    __syncthreads();
  }
  if (threadIdx.x == 0) atomicAdd(&scal[1], red[0]);
}

// --- pass 2: wave owns 32 codes (2 groups x 16), sweeps a 1024-row split.
//     accP = sum_t 2^(fb-lse2) per code; accE = sum p*dl (sample entropy). ---
__global__ __launch_bounds__(256) void k_pass2(
    const short* __restrict__ eh, const short* __restrict__ el,
    const short* __restrict__ zh, const short* __restrict__ zl,
    const float* __restrict__ ses2, const float* __restrict__ c2,
    float* __restrict__ avg, float* __restrict__ scal) {
  const int lane = threadIdx.x & 63, wv = threadIdx.x >> 6;
  const int q = lane >> 4, c = lane & 15;
  const int cbase = blockIdx.x * 128 + wv * 32;
  const int tb0 = blockIdx.y * (T / RS2);

  s16x8 ah0 = *(const s16x8*)(eh + (size_t)(cbase + c) * ED + q * 8);
  s16x8 al0 = *(const s16x8*)(el + (size_t)(cbase + c) * ED + q * 8);
  s16x8 ah1 = *(const s16x8*)(eh + (size_t)(cbase + 16 + c) * ED + q * 8);
  s16x8 al1 = *(const s16x8*)(el + (size_t)(cbase + 16 + c) * ED + q * 8);

  float sgr[8];
#pragma unroll
  for (int g = 0; g < 2; ++g)
#pragma unroll
    for (int r = 0; r < 4; ++r)
      sgr[g * 4 + r] = ses2[cbase + g * 16 + q * 4 + r];

  float accP[8], accE[8];
#pragma unroll
  for (int k = 0; k < 8; ++k) { accP[k] = 0.f; accE[k] = 0.f; }

  for (int tile = 0; tile < (T / RS2) / 16; ++tile) {
    const int tb = tb0 + tile * 16;
    s16x8 bh = *(const s16x8*)(zh + (size_t)(tb + c) * ED + q * 8);
    s16x8 bl = *(const s16x8*)(zl + (size_t)(tb + c) * ED + q * 8);
    float cc = c2[tb + c];
    f32x4 acc0 = {0.f, 0.f, 0.f, 0.f}, acc1 = {0.f, 0.f, 0.f, 0.f};
    acc0 = __builtin_amdgcn_mfma_f32_16x16x32_bf16(ah0, bh, acc0, 0, 0, 0);
    acc1 = __builtin_amdgcn_mfma_f32_16x16x32_bf16(ah1, bh, acc1, 0, 0, 0);
    acc0 = __builtin_amdgcn_mfma_f32_16x16x32_bf16(al0, bh, acc0, 0, 0, 0);
    acc1 = __builtin_amdgcn_mfma_f32_16x16x32_bf16(al1, bh, acc1, 0, 0, 0);
    acc0 = __builtin_amdgcn_mfma_f32_16x16x32_bf16(ah0, bl, acc0, 0, 0, 0);
    acc1 = __builtin_amdgcn_mfma_f32_16x16x32_bf16(ah1, bl, acc1, 0, 0, 0);
#pragma unroll
    for (int g = 0; g < 2; ++g) {
#pragma unroll
      for (int r = 0; r < 4; ++r) {
        const int k = g * 4 + r;
        float v = (g == 0) ? acc0[r] : acc1[r];
        float dl = fmaf(K2, v, sgr[k] + cc);  // fb - lse2 (<=0); exp2->0 if tiny
        float p = fexp2(dl);
        accP[k] += p;
        accE[k] = fmaf(p, dl, accE[k]);
      }
    }
  }

  // per-lane entropy total BEFORE any cross-lane reduce of accP
  float etot = 0.f;
#pragma unroll
  for (int k = 0; k < 8; ++k) etot += accE[k];

#pragma unroll
  for (int d = 1; d < 16; d <<= 1) {
#pragma unroll
    for (int k = 0; k < 8; ++k) accP[k] += __shfl_xor(accP[k], d);
  }
#pragma unroll
  for (int k = 0; k < 8; ++k) {
    if (c == k) {
      const int g = k >> 2, r = k & 3;
      atomicAdd(&avg[cbase + g * 16 + q * 4 + r], accP[k]);
    }
  }
  __shared__ float red[256];
  red[threadIdx.x] = etot;
  __syncthreads();
  for (int st = 128; st > 0; st >>= 1) {
    if (threadIdx.x < st) red[threadIdx.x] += red[threadIdx.x + st];
    __syncthreads();
  }
  if (threadIdx.x == 0) atomicAdd(&scal[0], red[0]);
}

// --- straight-through output, back to (b,c,h,w). ---
__global__ __launch_bounds__(256) void k_out(const float* __restrict__ zf,
    const float* __restrict__ embn, const int* __restrict__ idxo,
    float* __restrict__ out) {
  int o = blockIdx.x * 256 + threadIdx.x;
  int c = (o >> 8) & 31;
  int t = ((o >> 13) << 8) | (o & 255);
  float zv = zf[(size_t)t * ED + c];
  float qv = embn[(size_t)idxo[t] * ED + c];
  out[o] = zv + (qv - zv);
}

// --- final scalars. ---
__global__ __launch_bounds__(256) void k_final(const float* __restrict__ avg,
    const float* __restrict__ scal, float* __restrict__ out) {
  float s = 0.f;
  for (int i = threadIdx.x; i < N_E; i += 256) {
    float a = avg[i] * (1.0f / T);
    s += a * (flog2(a + 1e-5f) * LN2);
  }
  __shared__ float red[256];
  red[threadIdx.x] = s;
  __syncthreads();
  for (int st = 128; st > 0; st >>= 1) {
    if (threadIdx.x < st) red[threadIdx.x] += red[threadIdx.x + st];
    __syncthreads();
  }
  if (threadIdx.x == 0) {
    float avg_entropy = -red[0];
    float sample_entropy = -(scal[0] * LN2) * (1.0f / T);
    float vq = scal[1] * (1.0f / (T * ED));
    out[T * ED + 0] = vq;
    out[T * ED + 1] = 0.25f * vq;
    out[T * ED + 2] = 0.1f * (sample_entropy - avg_entropy);
  }
}

extern "C" void kernel_launch(void* const* d_in, const int* in_sizes, int n_in,
                              void* d_out, int out_size, void* d_ws, size_t ws_size,
                              hipStream_t stream) {
  const float* z = (const float*)d_in[0];
  const float* emb = (const float*)d_in[1];
  float* out = (float*)d_out;
  float* w = (float*)d_ws;

  float* embn = w;                          // 524288 f
  float* ses2 = embn + 524288;              // 16384
  float* zf   = ses2 + 16384;               // 262144
  float* a02  = zf + 262144;                // 8192
  short* ehi  = (short*)(a02 + 8192);       // 524288 sh (262144 f)
  short* elo  = ehi + 524288;               // 524288 sh
  short* zhi  = elo + 524288;               // 262144 sh (131072 f)
  short* zlo  = zhi + 262144;               // 262144 sh
  float* pm1  = (float*)(zlo + 262144);     // NS1*T = 131072 f
  float* pm2  = pm1 + NS1 * T;              // 131072
  float* pZ   = pm2 + NS1 * T;              // 131072
  int*   pi1  = (int*)(pZ + NS1 * T);       // 131072
  int*   pi2  = pi1 + NS1 * T;              // 131072
  float* c2   = (float*)(pi2 + NS1 * T);    // 8192
  int*   idxo = (int*)(c2 + 8192);          // 8192
  float* avg  = (float*)(idxo + 8192);      // 16384
  float* scal = avg + 16384;                // 2     (~9.1 MB total)

  hipMemsetAsync(avg, 0, (16384 + 2) * sizeof(float), stream);

  k_prep_emb<<<64, 256, 0, stream>>>(emb, embn, ses2, ehi, elo);
  k_prep_z<<<32, 256, 0, stream>>>(z, zf, a02, zhi, zlo);
  k_pass1<<<dim3(T / 128, NS1), 256, 0, stream>>>(ehi, elo, zhi, zlo, ses2, a02,
                                                  pm1, pm2, pZ, pi1, pi2);
  k_merge<<<32, 256, 0, stream>>>(pm1, pm2, pZ, pi1, pi2, zf, embn, ses2, a02,
                                  c2, idxo, scal);
  k_pass2<<<dim3(N_E / 128, RS2), 256, 0, stream>>>(ehi, elo, zhi, zlo, ses2,
                                                    c2, avg, scal);
  k_out<<<1024, 256, 0, stream>>>(zf, embn, idxo, out);
  k_final<<<1, 256, 0, stream>>>(avg, scal, out);
}

// Round 6
// 234.761 us; speedup vs baseline: 10.1784x; 1.0258x over previous
//
#include <hip/hip_runtime.h>

// VQ-VAE vector quantize + losses, MI355X.
// T=8192 rows, N_E=16384 codes, D=32.
// R6: prefetched MFMA sweeps. bf16 hi/lo split (3x mfma_f32_16x16x32_bf16),
//     K2 prescaled into z-side split, bias folded into MFMA C operand,
//     med3 top-2, interleaved [row][g][hi8|lo8] operand layout, k_out folded
//     into k_merge. Top-2 + exact fp32 refine protects argmin (R5-proven).

#define N_E 16384
#define ED 32
#define T 8192
#define NS1 16      // pass-1 code splits (1024 codes each)
#define RS2 8       // pass-2 row splits  (1024 rows each)

#define K2 288.53900817779268f    // 200 * log2(e)
#define NS2F -144.26950408889634f // -100 * log2(e)
#define LN2 0.6931471805599453f

typedef __attribute__((ext_vector_type(8))) short s16x8;
typedef __attribute__((ext_vector_type(4))) float f32x4;

__device__ __forceinline__ float fexp2(float x) { return __builtin_amdgcn_exp2f(x); }
__device__ __forceinline__ float flog2(float x) { return __builtin_amdgcn_logf(x); }
__device__ __forceinline__ float fmed3(float a, float b, float c) {
  return __builtin_amdgcn_fmed3f(a, b, c);
}

__device__ __forceinline__ unsigned short f2bf(float x) {
  unsigned u = __float_as_uint(x);
  unsigned r = (u + 0x7FFFu + ((u >> 16) & 1u)) >> 16;
  return (unsigned short)r;
}
__device__ __forceinline__ float bf2f(unsigned short h) {
  return __uint_as_float(((unsigned)h) << 16);
}

// exact fp32 dot of a streamed row with 8 resident float4s (by value)
__device__ __forceinline__ float dot32x(const float* __restrict__ p,
    float4 z0, float4 z1, float4 z2, float4 z3,
    float4 z4, float4 z5, float4 z6, float4 z7) {
  const float4* e = (const float4*)p;
  float a0 = 0.f, a1 = 0.f, a2 = 0.f, a3 = 0.f; float4 q;
  q = e[0]; a0 = fmaf(q.x, z0.x, a0); a0 = fmaf(q.y, z0.y, a0);
            a0 = fmaf(q.z, z0.z, a0); a0 = fmaf(q.w, z0.w, a0);
  q = e[1]; a1 = fmaf(q.x, z1.x, a1); a1 = fmaf(q.y, z1.y, a1);
            a1 = fmaf(q.z, z1.z, a1); a1 = fmaf(q.w, z1.w, a1);
  q = e[2]; a2 = fmaf(q.x, z2.x, a2); a2 = fmaf(q.y, z2.y, a2);
            a2 = fmaf(q.z, z2.z, a2); a2 = fmaf(q.w, z2.w, a2);
  q = e[3]; a3 = fmaf(q.x, z3.x, a3); a3 = fmaf(q.y, z3.y, a3);
            a3 = fmaf(q.z, z3.z, a3); a3 = fmaf(q.w, z3.w, a3);
  q = e[4]; a0 = fmaf(q.x, z4.x, a0); a0 = fmaf(q.y, z4.y, a0);
            a0 = fmaf(q.z, z4.z, a0); a0 = fmaf(q.w, z4.w, a0);
  q = e[5]; a1 = fmaf(q.x, z5.x, a1); a1 = fmaf(q.y, z5.y, a1);
            a1 = fmaf(q.z, z5.z, a1); a1 = fmaf(q.w, z5.w, a1);
  q = e[6]; a2 = fmaf(q.x, z6.x, a2); a2 = fmaf(q.y, z6.y, a2);
            a2 = fmaf(q.z, z6.z, a2); a2 = fmaf(q.w, z6.w, a2);
  q = e[7]; a3 = fmaf(q.x, z7.x, a3); a3 = fmaf(q.y, z7.y, a3);
            a3 = fmaf(q.z, z7.z, a3); a3 = fmaf(q.w, z7.w, a3);
  return (a0 + a1) + (a2 + a3);
}

// split 8 floats (scaled by sc) into hi/lo bf16 groups and store interleaved
__device__ __forceinline__ void split_store(short* __restrict__ base,
    size_t row, int g, float4 va, float4 vb, float sc) {
  float f[8] = { va.x * sc, va.y * sc, va.z * sc, va.w * sc,
                 vb.x * sc, vb.y * sc, vb.z * sc, vb.w * sc };
  s16x8 H, L;
#pragma unroll
  for (int e = 0; e < 8; ++e) {
    unsigned short h = f2bf(f[e]);
    H[e] = (short)h;
    L[e] = (short)f2bf(f[e] - bf2f(h));
  }
  s16x8* p = (s16x8*)base + row * 8 + g * 2;
  p[0] = H; p[1] = L;
}

// --- prep: normalize embedding rows; fp32 + interleaved bf16 hi/lo + ses2 ---
__global__ __launch_bounds__(256) void k_prep_emb(const float* __restrict__ emb,
    float* __restrict__ embn, float* __restrict__ ses2, short* __restrict__ ehl) {
  int n = blockIdx.x * 256 + threadIdx.x;
  const float4* r4 = (const float4*)(emb + (size_t)n * ED);
  float4 v[8]; float s = 0.f;
#pragma unroll
  for (int j = 0; j < 8; ++j) {
    v[j] = r4[j];
    s = fmaf(v[j].x, v[j].x, s); s = fmaf(v[j].y, v[j].y, s);
    s = fmaf(v[j].z, v[j].z, s); s = fmaf(v[j].w, v[j].w, s);
  }
  float inv = 1.0f / fmaxf(sqrtf(s), 1e-12f);
  float s2 = 0.f;
  float4* o4 = (float4*)(embn + (size_t)n * ED);
#pragma unroll
  for (int j = 0; j < 8; ++j) {
    float4 w; w.x = v[j].x * inv; w.y = v[j].y * inv;
    w.z = v[j].z * inv; w.w = v[j].w * inv;
    o4[j] = w; v[j] = w;
    s2 = fmaf(w.x, w.x, s2); s2 = fmaf(w.y, w.y, s2);
    s2 = fmaf(w.z, w.z, s2); s2 = fmaf(w.w, w.w, s2);
  }
  ses2[n] = NS2F * s2;
#pragma unroll
  for (int g = 0; g < 4; ++g)
    split_store(ehl, (size_t)n, g, v[2 * g], v[2 * g + 1], 1.0f);
}

// --- prep: transpose+normalize z; fp32 zf + K2-prescaled bf16 hi/lo + a02 ---
__global__ __launch_bounds__(256) void k_prep_z(const float* __restrict__ z,
    float* __restrict__ zf, float* __restrict__ a02, short* __restrict__ zhl) {
  int t = blockIdx.x * 256 + threadIdx.x;
  int b = t >> 8, hw = t & 255;
  const float* base = z + (size_t)b * (ED * 256) + hw;
  float4 v[8]; float s = 0.f;
#pragma unroll
  for (int j = 0; j < 8; ++j) {
    float4 w;
    w.x = base[(4 * j + 0) * 256]; w.y = base[(4 * j + 1) * 256];
    w.z = base[(4 * j + 2) * 256]; w.w = base[(4 * j + 3) * 256];
    v[j] = w;
    s = fmaf(w.x, w.x, s); s = fmaf(w.y, w.y, s);
    s = fmaf(w.z, w.z, s); s = fmaf(w.w, w.w, s);
  }
  float inv = 1.0f / fmaxf(sqrtf(s), 1e-12f);
  float s2 = 0.f;
  float4* o4 = (float4*)(zf + (size_t)t * ED);
#pragma unroll
  for (int j = 0; j < 8; ++j) {
    float4 w; w.x = v[j].x * inv; w.y = v[j].y * inv;
    w.z = v[j].z * inv; w.w = v[j].w * inv;
    o4[j] = w; v[j] = w;
    s2 = fmaf(w.x, w.x, s2); s2 = fmaf(w.y, w.y, s2);
    s2 = fmaf(w.z, w.z, s2); s2 = fmaf(w.w, w.w, s2);
  }
  a02[t] = NS2F * s2;
#pragma unroll
  for (int g = 0; g < 4; ++g)
    split_store(zhl, (size_t)t, g, v[2 * g], v[2 * g + 1], K2);
}

// --- pass 1: wave owns 32 rows, sweeps a 1024-code split in 16-code tiles.
//     acc C-init = a02+80; fb = acc + ses2[code]. med3 top-2 + biased Z. ---
__global__ __launch_bounds__(256, 4) void k_pass1(
    const short* __restrict__ ehl, const short* __restrict__ zhl,
    const float* __restrict__ ses2, const float* __restrict__ a02,
    float* __restrict__ pm1, float* __restrict__ pm2, float* __restrict__ pZ,
    int* __restrict__ pi1, int* __restrict__ pi2) {
  const int lane = threadIdx.x & 63, wv = threadIdx.x >> 6;
  const int q = lane >> 4, c = lane & 15;
  const int rowbase = blockIdx.x * 128 + wv * 32;
  const int nb0 = blockIdx.y * (N_E / NS1);
  const int NT = (N_E / NS1) / 16;  // 64

  const s16x8* zg = (const s16x8*)zhl;
  const int aidx = (rowbase + c) * 8 + q * 2;
  s16x8 ah0 = zg[aidx], al0 = zg[aidx + 1];
  s16x8 ah1 = zg[aidx + 128], al1 = zg[aidx + 129];   // +16 rows

  f32x4 bias0, bias1;
#pragma unroll
  for (int r = 0; r < 4; ++r) {
    bias0[r] = a02[rowbase + q * 4 + r] + 80.0f;
    bias1[r] = a02[rowbase + 16 + q * 4 + r] + 80.0f;
  }

  float m1[8], m2[8], Zs[8]; int i1[8], i2[8];
#pragma unroll
  for (int k = 0; k < 8; ++k) {
    m1[k] = -1e30f; m2[k] = -1e30f; Zs[k] = 0.f;
    i1[k] = nb0 + c; i2[k] = nb0 + c;
  }

  const s16x8* eg = (const s16x8*)ehl;
  const int bbase = (nb0 + c) * 8 + q * 2;
  s16x8 bh = eg[bbase], bl = eg[bbase + 1];
  float sesc = ses2[nb0 + c];

  for (int tile = 0; tile < NT; ++tile) {
    const int nx = (tile + 1 < NT) ? tile + 1 : tile;     // uniform
    const int nidx = bbase + nx * 128;
    s16x8 nh = eg[nidx], nl = eg[nidx + 1];               // prefetch
    float nses = ses2[nb0 + nx * 16 + c];

    f32x4 acc0 = __builtin_amdgcn_mfma_f32_16x16x32_bf16(ah0, bh, bias0, 0, 0, 0);
    f32x4 acc1 = __builtin_amdgcn_mfma_f32_16x16x32_bf16(ah1, bh, bias1, 0, 0, 0);
    acc0 = __builtin_amdgcn_mfma_f32_16x16x32_bf16(al0, bh, acc0, 0, 0, 0);
    acc1 = __builtin_amdgcn_mfma_f32_16x16x32_bf16(al1, bh, acc1, 0, 0, 0);
    acc0 = __builtin_amdgcn_mfma_f32_16x16x32_bf16(ah0, bl, acc0, 0, 0, 0);
    acc1 = __builtin_amdgcn_mfma_f32_16x16x32_bf16(ah1, bl, acc1, 0, 0, 0);

    const int vn = nb0 + tile * 16 + c;
#pragma unroll
    for (int g = 0; g < 2; ++g) {
#pragma unroll
      for (int r = 0; r < 4; ++r) {
        const int k = g * 4 + r;
        float fb = ((g == 0) ? acc0[r] : acc1[r]) + sesc;
        bool g1 = fb > m1[k];
        bool g2 = fb > m2[k];
        i2[k] = g1 ? i1[k] : (g2 ? vn : i2[k]);
        m2[k] = fmed3(fb, m1[k], m2[k]);   // 2nd-max of {m1,m2,fb}
        i1[k] = g1 ? vn : i1[k];
        m1[k] = fmaxf(m1[k], fb);
        Zs[k] += fexp2(fb);
      }
    }
    bh = nh; bl = nl; sesc = nses;
  }

  // reduce across the 16 cols within each quad
#pragma unroll
  for (int d = 1; d < 16; d <<= 1) {
#pragma unroll
    for (int k = 0; k < 8; ++k) {
      float om1 = __shfl_xor(m1[k], d);
      float om2 = __shfl_xor(m2[k], d);
      float oZ = __shfl_xor(Zs[k], d);
      int oi1 = __shfl_xor(i1[k], d);
      int oi2 = __shfl_xor(i2[k], d);
      bool c1 = om1 > m1[k];
      float lm = c1 ? m1[k] : om1;
      int li = c1 ? i1[k] : oi1;
      float nm1 = c1 ? om1 : m1[k];
      int ni1 = c1 ? oi1 : i1[k];
      bool cb = om2 > m2[k];
      float mm2 = cb ? om2 : m2[k];
      int mi2 = cb ? oi2 : i2[k];
      bool c3 = mm2 > lm;
      m1[k] = nm1; i1[k] = ni1;
      m2[k] = c3 ? mm2 : lm;
      i2[k] = c3 ? mi2 : li;
      Zs[k] += oZ;
    }
  }

#pragma unroll
  for (int k = 0; k < 8; ++k) {
    if (c == k) {
      const int g = k >> 2, r = k & 3;
      const int t = rowbase + g * 16 + q * 4 + r;
      const int p = blockIdx.y * T + t;
      pm1[p] = m1[k]; pm2[p] = m2[k]; pZ[p] = Zs[k];
      pi1[p] = i1[k]; pi2[p] = i2[k];
    }
  }
}

// --- merge: combine split partials; exact fp32 re-compare of candidates;
//     lse2, c2 = a02 - lse2, vq sum-of-squares, straight-through output. ---
__global__ __launch_bounds__(256) void k_merge(
    const float* __restrict__ pm1, const float* __restrict__ pm2,
    const float* __restrict__ pZ, const int* __restrict__ pi1,
    const int* __restrict__ pi2, const float* __restrict__ zf,
    const float* __restrict__ embn, const float* __restrict__ ses2,
    const float* __restrict__ a02, float* __restrict__ c2,
    int* __restrict__ idxo, float* __restrict__ scal, float* __restrict__ out) {
  const int t = blockIdx.x * 256 + threadIdx.x;
  float m1 = -1e30f, m2 = -1e30f, Z = 0.f;
  int i1 = 0, i2 = 0;
  for (int s = 0; s < NS1; ++s) {
    const int p = s * T + t;
    float sm1 = pm1[p], sm2 = pm2[p];
    int si1 = pi1[p], si2 = pi2[p];
    Z += pZ[p];
    bool c1 = sm1 > m1;
    float lm = c1 ? m1 : sm1;
    int li = c1 ? i1 : si1;
    float nm1 = c1 ? sm1 : m1;
    int ni1 = c1 ? si1 : i1;
    bool cb = sm2 > m2;
    float mm2 = cb ? sm2 : m2;
    int mi2 = cb ? si2 : i2;
    bool c3 = mm2 > lm;
    m1 = nm1; i1 = ni1;
    m2 = c3 ? mm2 : lm;
    i2 = c3 ? mi2 : li;
  }
  const float a02t = a02[t];
  const float lse2 = flog2(Z) - 80.0f;
  c2[t] = a02t - lse2;

  const float4* zr4 = (const float4*)(zf + (size_t)t * ED);
  float4 z0 = zr4[0], z1 = zr4[1], z2 = zr4[2], z3 = zr4[3];
  float4 z4 = zr4[4], z5 = zr4[5], z6 = zr4[6], z7 = zr4[7];
  float d1 = dot32x(embn + (size_t)i1 * ED, z0, z1, z2, z3, z4, z5, z6, z7);
  float d2 = dot32x(embn + (size_t)i2 * ED, z0, z1, z2, z3, z4, z5, z6, z7);
  float fb1 = fmaf(K2, d1, a02t + ses2[i1]);
  float fb2 = fmaf(K2, d2, a02t + ses2[i2]);
  int bi = (fb2 > fb1 || (fb2 == fb1 && i2 < i1)) ? i2 : i1;
  idxo[t] = bi;

  // vq sum-of-squares + straight-through output (out = zb + (z_q - zb))
  const int b = t >> 8, hw = t & 255;
  float* ob = out + (size_t)b * (ED * 256) + hw;
  float ss = 0.f;
  const float4* e4 = (const float4*)(embn + (size_t)bi * ED);
#pragma unroll
  for (int j = 0; j < 8; ++j) {
    float4 qv = e4[j];
    float4 zv = (j == 0) ? z0 : (j == 1) ? z1 : (j == 2) ? z2 : (j == 3) ? z3
              : (j == 4) ? z4 : (j == 5) ? z5 : (j == 6) ? z6 : z7;
    float df;
    df = qv.x - zv.x; ss = fmaf(df, df, ss); ob[(4 * j + 0) * 256] = zv.x + (qv.x - zv.x);
    df = qv.y - zv.y; ss = fmaf(df, df, ss); ob[(4 * j + 1) * 256] = zv.y + (qv.y - zv.y);
    df = qv.z - zv.z; ss = fmaf(df, df, ss); ob[(4 * j + 2) * 256] = zv.z + (qv.z - zv.z);
    df = qv.w - zv.w; ss = fmaf(df, df, ss); ob[(4 * j + 3) * 256] = zv.w + (qv.w - zv.w);
  }
  __shared__ float red[256];
  red[threadIdx.x] = ss;
  __syncthreads();
  for (int st = 128; st > 0; st >>= 1) {
    if (threadIdx.x < st) red[threadIdx.x] += red[threadIdx.x + st];
    __syncthreads();
  }
  if (threadIdx.x == 0) atomicAdd(&scal[1], red[0]);
}

// --- pass 2: wave owns 32 codes, sweeps a 1024-row split in 16-row tiles.
//     acc C-init = ses2[code]; dl = acc + c2[t] = fb - lse2. ---
__global__ __launch_bounds__(256, 4) void k_pass2(
    const short* __restrict__ ehl, const short* __restrict__ zhl,
    const float* __restrict__ ses2, const float* __restrict__ c2,
    float* __restrict__ avg, float* __restrict__ scal) {
  const int lane = threadIdx.x & 63, wv = threadIdx.x >> 6;
  const int q = lane >> 4, c = lane & 15;
  const int cbase = blockIdx.x * 128 + wv * 32;
  const int tb0 = blockIdx.y * (T / RS2);
  const int NT = (T / RS2) / 16;  // 64

  const s16x8* eg = (const s16x8*)ehl;
  const int aidx = (cbase + c) * 8 + q * 2;
  s16x8 ah0 = eg[aidx], al0 = eg[aidx + 1];
  s16x8 ah1 = eg[aidx + 128], al1 = eg[aidx + 129];

  f32x4 sg0, sg1;
#pragma unroll
  for (int r = 0; r < 4; ++r) {
    sg0[r] = ses2[cbase + q * 4 + r];
    sg1[r] = ses2[cbase + 16 + q * 4 + r];
  }

  float accP[8], accE[8];
#pragma unroll
  for (int k = 0; k < 8; ++k) { accP[k] = 0.f; accE[k] = 0.f; }

  const s16x8* zg = (const s16x8*)zhl;
  const int bbase = (tb0 + c) * 8 + q * 2;
  s16x8 bh = zg[bbase], bl = zg[bbase + 1];
  float cc = c2[tb0 + c];

  for (int tile = 0; tile < NT; ++tile) {
    const int nx = (tile + 1 < NT) ? tile + 1 : tile;
    const int nidx = bbase + nx * 128;
    s16x8 nh = zg[nidx], nl = zg[nidx + 1];               // prefetch
    float ncc = c2[tb0 + nx * 16 + c];

    f32x4 acc0 = __builtin_amdgcn_mfma_f32_16x16x32_bf16(ah0, bh, sg0, 0, 0, 0);
    f32x4 acc1 = __builtin_amdgcn_mfma_f32_16x16x32_bf16(ah1, bh, sg1, 0, 0, 0);
    acc0 = __builtin_amdgcn_mfma_f32_16x16x32_bf16(al0, bh, acc0, 0, 0, 0);
    acc1 = __builtin_amdgcn_mfma_f32_16x16x32_bf16(al1, bh, acc1, 0, 0, 0);
    acc0 = __builtin_amdgcn_mfma_f32_16x16x32_bf16(ah0, bl, acc0, 0, 0, 0);
    acc1 = __builtin_amdgcn_mfma_f32_16x16x32_bf16(ah1, bl, acc1, 0, 0, 0);

#pragma unroll
    for (int g = 0; g < 2; ++g) {
#pragma unroll
      for (int r = 0; r < 4; ++r) {
        const int k = g * 4 + r;
        float dl = ((g == 0) ? acc0[r] : acc1[r]) + cc;  // fb - lse2 (<=0)
        float p = fexp2(dl);                              // underflow -> 0
        accP[k] += p;
        accE[k] = fmaf(p, dl, accE[k]);
      }
    }
    bh = nh; bl = nl; cc = ncc;
  }

  float etot = 0.f;
#pragma unroll
  for (int k = 0; k < 8; ++k) etot += accE[k];

#pragma unroll
  for (int d = 1; d < 16; d <<= 1) {
#pragma unroll
    for (int k = 0; k < 8; ++k) accP[k] += __shfl_xor(accP[k], d);
  }
#pragma unroll
  for (int k = 0; k < 8; ++k) {
    if (c == k) {
      const int g = k >> 2, r = k & 3;
      atomicAdd(&avg[cbase + g * 16 + q * 4 + r], accP[k]);
    }
  }
  __shared__ float red[256];
  red[threadIdx.x] = etot;
  __syncthreads();
  for (int st = 128; st > 0; st >>= 1) {
    if (threadIdx.x < st) red[threadIdx.x] += red[threadIdx.x + st];
    __syncthreads();
  }
  if (threadIdx.x == 0) atomicAdd(&scal[0], red[0]);
}

// --- final scalars. ---
__global__ __launch_bounds__(256) void k_final(const float* __restrict__ avg,
    const float* __restrict__ scal, float* __restrict__ out) {
  float s = 0.f;
  for (int i = threadIdx.x; i < N_E; i += 256) {
    float a = avg[i] * (1.0f / T);
    s += a * (flog2(a + 1e-5f) * LN2);
  }
  __shared__ float red[256];
  red[threadIdx.x] = s;
  __syncthreads();
  for (int st = 128; st > 0; st >>= 1) {
    if (threadIdx.x < st) red[threadIdx.x] += red[threadIdx.x + st];
    __syncthreads();
  }
  if (threadIdx.x == 0) {
    float avg_entropy = -red[0];
    float sample_entropy = -(scal[0] * LN2) * (1.0f / T);
    float vq = scal[1] * (1.0f / (T * ED));
    out[T * ED + 0] = vq;
    out[T * ED + 1] = 0.25f * vq;
    out[T * ED + 2] = 0.1f * (sample_entropy - avg_entropy);
  }
}

extern "C" void kernel_launch(void* const* d_in, const int* in_sizes, int n_in,
                              void* d_out, int out_size, void* d_ws, size_t ws_size,
                              hipStream_t stream) {
  const float* z = (const float*)d_in[0];
  const float* emb = (const float*)d_in[1];
  float* out = (float*)d_out;
  float* w = (float*)d_ws;

  float* embn = w;                          // 524288 f
  float* ses2 = embn + 524288;              // 16384
  float* zf   = ses2 + 16384;               // 262144
  float* a02  = zf + 262144;                // 8192
  short* ehl  = (short*)(a02 + 8192);       // 1048576 sh (524288 f)
  short* zhl  = ehl + 1048576;              // 524288 sh  (262144 f)
  float* pm1  = (float*)(zhl + 524288);     // NS1*T = 131072 f
  float* pm2  = pm1 + NS1 * T;              // 131072
  float* pZ   = pm2 + NS1 * T;              // 131072
  int*   pi1  = (int*)(pZ + NS1 * T);       // 131072
  int*   pi2  = pi1 + NS1 * T;              // 131072
  float* c2   = (float*)(pi2 + NS1 * T);    // 8192
  int*   idxo = (int*)(c2 + 8192);          // 8192
  float* avg  = (float*)(idxo + 8192);      // 16384
  float* scal = avg + 16384;                // 2     (~9.1 MB total)

  hipMemsetAsync(avg, 0, (16384 + 2) * sizeof(float), stream);

  k_prep_emb<<<64, 256, 0, stream>>>(emb, embn, ses2, ehl);
  k_prep_z<<<32, 256, 0, stream>>>(z, zf, a02, zhl);
  k_pass1<<<dim3(T / 128, NS1), 256, 0, stream>>>(ehl, zhl, ses2, a02,
                                                  pm1, pm2, pZ, pi1, pi2);
  k_merge<<<32, 256, 0, stream>>>(pm1, pm2, pZ, pi1, pi2, zf, embn, ses2, a02,
                                  c2, idxo, scal, out);
  k_pass2<<<dim3(N_E / 128, RS2), 256, 0, stream>>>(ehl, zhl, ses2, c2, avg, scal);
  k_final<<<1, 256, 0, stream>>>(avg, scal, out);
}